// Round 2
// baseline (365.161 us; speedup 1.0000x reference)
//
#include <hip/hip_runtime.h>

typedef __attribute__((ext_vector_type(8))) short short8;    // bf16x8 MFMA frag
typedef __attribute__((ext_vector_type(8))) unsigned short ushort8;
typedef __attribute__((ext_vector_type(4))) unsigned short ushort4v;
typedef __attribute__((ext_vector_type(4))) float f32x4;
typedef unsigned short ushort;

__device__ __forceinline__ ushort f2bf(float f) {
  union { float f; unsigned u; } a; a.f = f;
  unsigned r = a.u + 0x7fffu + ((a.u >> 16) & 1u);
  return (ushort)(r >> 16);
}

__device__ __forceinline__ void gload16(const void* g, void* l) {
  __builtin_amdgcn_global_load_lds((const __attribute__((address_space(1))) void*)g,
                                   (__attribute__((address_space(3))) void*)l, 16, 0, 0);
}

// ---------------- segment starts (batch sorted & contiguous) ----------------
__global__ __launch_bounds__(256) void seg_start_k(const int* __restrict__ batch,
                                                   int* __restrict__ start) {
  const int i = blockIdx.x * 256 + threadIdx.x;
  const int b = batch[i];
  if (i == 0 || batch[i - 1] != b) start[b] = i;
  if (i == 0) start[256] = 65536;
}

// ---------------- weight transpose + bf16 convert ----------------
__global__ __launch_bounds__(256) void prep_w_k(
    const float* __restrict__ Wq, const float* __restrict__ Wk,
    const float* __restrict__ Wv, const float* __restrict__ Wo,
    const float* __restrict__ W1, const float* __restrict__ W2,
    ushort* __restrict__ Wt) {
  const int w = blockIdx.y;
  const float* src; ushort* dst; int Kd, Nd;
  switch (w) {
    case 0: src = Wq; dst = Wt;          Kd = 256; Nd = 256; break;
    case 1: src = Wk; dst = Wt + 65536;  Kd = 256; Nd = 256; break;
    case 2: src = Wv; dst = Wt + 131072; Kd = 256; Nd = 256; break;
    case 3: src = Wo; dst = Wt + 196608; Kd = 256; Nd = 256; break;
    case 4: src = W1; dst = Wt + 262144; Kd = 256; Nd = 512; break;
    default: src = W2; dst = Wt + 393216; Kd = 512; Nd = 256; break;
  }
  const int e = blockIdx.x * 256 + threadIdx.x;
  if (e < Kd * Nd) {
    const int k = e / Nd, n = e - k * Nd;
    dst[n * Kd + k] = f2bf(src[e]);
  }
}

// ---------------- pack x -> dense bf16 [G*257][256] ----------------
__global__ __launch_bounds__(256) void pack_xd_k(
    const float* __restrict__ x, const float* __restrict__ cls,
    const int* __restrict__ start, ushort* __restrict__ xd) {
  const size_t idx = (((size_t)blockIdx.x << 8) + threadIdx.x) << 3;  // 8 cols/thread
  const int row = (int)(idx >> 8);
  const int col = (int)(idx & 255);
  const int g = row / 257, n = row - g * 257;
  const int sg = start[g], cn = start[g + 1] - sg;
  float4 a, b;
  if (n < cn) {
    const float* src = x + (((size_t)(sg + n)) << 8) + col;
    a = ((const float4*)src)[0]; b = ((const float4*)src)[1];
  } else if (n == 256) {
    const float* src = cls + (((size_t)g) << 8) + col;
    a = ((const float4*)src)[0]; b = ((const float4*)src)[1];
  } else {
    a.x = a.y = a.z = a.w = 0.f; b = a;
  }
  ushort8 o;
  o[0] = f2bf(a.x); o[1] = f2bf(a.y); o[2] = f2bf(a.z); o[3] = f2bf(a.w);
  o[4] = f2bf(b.x); o[5] = f2bf(b.y); o[6] = f2bf(b.z); o[7] = f2bf(b.w);
  *(ushort8*)(xd + idx) = o;
}

// ---------------- GEMM: C[M,N] = A[M,K](bf16) x Bt[N,K](bf16)^T + epilogue ----------------
// EPI 0: +bias -> bf16 (z in {0,1,2} selects Wq/Wk/Wv outputs)
// EPI 1: +bias + x_dense residual -> permuted fp32 store (h_pre)
// EPI 2: relu(+bias) -> bf16
// EPI 3: +bias + resid -> fp32 (of32 may alias resid: element read-then-write by owner)
template<int EPI>
__global__ __launch_bounds__(256, 2) void gemm_k(
    const ushort* __restrict__ A, const ushort* __restrict__ Bt,
    int N, int K,
    const float* __restrict__ b0, const float* __restrict__ b1, const float* __restrict__ b2,
    ushort* __restrict__ o0, ushort* __restrict__ o1, ushort* __restrict__ o2,
    float* __restrict__ of32,
    const float* __restrict__ x, const float* __restrict__ cls,
    const int* __restrict__ start, const float* __restrict__ resid) {
  __shared__ __align__(16) char As[16384];  // 128 rows x 128B, XOR-swizzled
  __shared__ __align__(16) char Bs[16384];
  const int tid = threadIdx.x, lane = tid & 63, wid = tid >> 6;
  const int wm = wid >> 1, wn = wid & 1;
  const int m0 = blockIdx.x * 128, n0 = blockIdx.y * 128;
  const int z = (EPI == 0) ? blockIdx.z : 0;
  const ushort* Bz = (EPI == 0) ? Bt + (size_t)z * 65536 : Bt;
  const float* bias = (EPI == 0) ? (z == 0 ? b0 : (z == 1 ? b1 : b2)) : b0;
  ushort* obf = (EPI == 0) ? (z == 0 ? o0 : (z == 1 ? o1 : o2)) : o0;

  f32x4 acc[4][4];
#pragma unroll
  for (int a = 0; a < 4; ++a)
#pragma unroll
    for (int b = 0; b < 4; ++b) acc[a][b] = (f32x4)0.0f;

  for (int kt = 0; kt < K; kt += 64) {
#pragma unroll
    for (int i = 0; i < 4; ++i) {
      const int L = (wid << 12) | (i << 10) | (lane << 4);
      const int r = L >> 7;
      const int cb = (L & 127) ^ ((r & 7) << 4);  // inverse-swizzled source col (bytes)
      gload16(A + (size_t)(m0 + r) * K + kt + (cb >> 1), As + L);
    }
#pragma unroll
    for (int i = 0; i < 4; ++i) {
      const int L = (wid << 12) | (i << 10) | (lane << 4);
      const int r = L >> 7;
      const int cb = (L & 127) ^ ((r & 7) << 4);
      gload16(Bz + (size_t)(n0 + r) * K + kt + (cb >> 1), Bs + L);
    }
    __syncthreads();
#pragma unroll
    for (int ks = 0; ks < 2; ++ks) {
      short8 af[4], bf_[4];
      const int cB = (ks * 32 + ((lane >> 4) << 3)) * 2;
#pragma unroll
      for (int t = 0; t < 4; ++t) {
        const int rA = wm * 64 + t * 16 + (lane & 15);
        af[t] = *(const short8*)(As + (rA << 7) + (cB ^ ((rA & 7) << 4)));
        const int rB = wn * 64 + t * 16 + (lane & 15);
        bf_[t] = *(const short8*)(Bs + (rB << 7) + (cB ^ ((rB & 7) << 4)));
      }
#pragma unroll
      for (int mt = 0; mt < 4; ++mt)
#pragma unroll
        for (int nt = 0; nt < 4; ++nt)
          acc[mt][nt] = __builtin_amdgcn_mfma_f32_16x16x32_bf16(af[mt], bf_[nt], acc[mt][nt], 0, 0, 0);
    }
    __syncthreads();
  }

  const int lr = (lane >> 4) << 2, lc = lane & 15;
#pragma unroll
  for (int mt = 0; mt < 4; ++mt) {
#pragma unroll
    for (int i = 0; i < 4; ++i) {
      const int m = m0 + wm * 64 + mt * 16 + lr + i;
      if constexpr (EPI == 1) {
        const int g = m / 257;
        const int nr = m - g * 257;
        const int sg = start[g];
        const int cn = start[g + 1] - sg;
#pragma unroll
        for (int nt = 0; nt < 4; ++nt) {
          const int n = n0 + wn * 64 + nt * 16 + lc;
          const float v = acc[mt][nt][i] + bias[n];
          if (nr < cn) {
            const size_t rr = (size_t)(sg + nr);
            of32[(rr << 8) + n] = v + x[(rr << 8) + n];
          } else if (nr == 256) {
            of32[(((size_t)(65536 + g)) << 8) + n] = v + cls[(((size_t)g) << 8) + n];
          }
        }
      } else {
#pragma unroll
        for (int nt = 0; nt < 4; ++nt) {
          const int n = n0 + wn * 64 + nt * 16 + lc;
          const float v = acc[mt][nt][i] + bias[n];
          if constexpr (EPI == 0) obf[(size_t)m * N + n] = f2bf(v);
          else if constexpr (EPI == 2) obf[(size_t)m * N + n] = f2bf(fmaxf(v, 0.0f));
          else of32[(size_t)m * N + n] = v + resid[(size_t)m * N + n];
        }
      }
    }
  }
}

// ---------------- attention: one block per (g, head); O may alias Q ----------------
#define KSTR 40
#define VSTR 296
#define PSTR 296
__global__ __launch_bounds__(256, 2) void attn_k(
    const ushort* __restrict__ Q, const ushort* __restrict__ Kb,
    const ushort* __restrict__ Vb, const int* __restrict__ start,
    ushort* __restrict__ O) {
  __shared__ __align__(16) ushort Ks[272 * KSTR];
  __shared__ __align__(16) ushort Vt[32 * VSTR];
  __shared__ __align__(16) ushort P[4][16 * PSTR];
  const int tid = threadIdx.x, lane = tid & 63, wid = tid >> 6;
  const int g = blockIdx.x >> 3, h = blockIdx.x & 7;
  const int cnt = start[g + 1] - start[g];
  const size_t base = ((size_t)g * 257) * 256 + h * 32;

  // stage K rows (pad rows 257..271 with zeros)
  for (int n = tid; n < 272; n += 256) {
    if (n < 257) {
      const ushort* src = Kb + base + ((size_t)n << 8);
#pragma unroll
      for (int j = 0; j < 4; ++j)
        *(ushort8*)(Ks + n * KSTR + j * 8) = *(const ushort8*)(src + j * 8);
    } else {
      const ushort8 zz = (ushort8)0;
#pragma unroll
      for (int j = 0; j < 4; ++j) *(ushort8*)(Ks + n * KSTR + j * 8) = zz;
    }
  }
  // stage V transposed: Vt[d][k]
  for (int n = tid; n < 288; n += 256) {
    if (n < 257) {
      const ushort* src = Vb + base + ((size_t)n << 8);
#pragma unroll
      for (int d = 0; d < 32; ++d) Vt[d * VSTR + n] = src[d];
    } else {
#pragma unroll
      for (int d = 0; d < 32; ++d) Vt[d * VSTR + n] = 0;
    }
  }
  // zero P pad cols 272..287 (per-wave buffer)
  for (int e = lane; e < 256; e += 64)
    P[wid][(e >> 4) * PSTR + 272 + (e & 15)] = 0;
  __syncthreads();

  const float scale = 0.17677669529663687f;  // 1/sqrt(32)
  for (int qt = wid; qt < 17; qt += 4) {
    const int qr = qt * 16 + (lane & 15);
    const int qc = qr < 257 ? qr : 256;
    const short8 qf = *(const short8*)(Q + base + ((size_t)qc << 8) + ((lane >> 4) << 3));

    f32x4 s[17];
#pragma unroll
    for (int kt = 0; kt < 17; ++kt) {
      const short8 kf = *(const short8*)(Ks + (kt * 16 + (lane & 15)) * KSTR + ((lane >> 4) << 3));
      s[kt] = __builtin_amdgcn_mfma_f32_16x16x32_bf16(qf, kf, (f32x4)0.0f, 0, 0, 0);
    }
#pragma unroll
    for (int kt = 0; kt < 17; ++kt) {
      const int n = kt * 16 + (lane & 15);
      const bool valid = (n < cnt) || (n == 256);
      s[kt] = valid ? s[kt] * scale : (f32x4)(-1e9f);
    }
    float mrow[4], den[4];
#pragma unroll
    for (int i = 0; i < 4; ++i) {
      float mv = s[0][i];
#pragma unroll
      for (int kt = 1; kt < 17; ++kt) mv = fmaxf(mv, s[kt][i]);
      mv = fmaxf(mv, __shfl_xor(mv, 1));
      mv = fmaxf(mv, __shfl_xor(mv, 2));
      mv = fmaxf(mv, __shfl_xor(mv, 4));
      mv = fmaxf(mv, __shfl_xor(mv, 8));
      mrow[i] = mv;
    }
#pragma unroll
    for (int kt = 0; kt < 17; ++kt) {
#pragma unroll
      for (int i = 0; i < 4; ++i) s[kt][i] = __expf(s[kt][i] - mrow[i]);
    }
#pragma unroll
    for (int i = 0; i < 4; ++i) {
      float sv = 0.f;
#pragma unroll
      for (int kt = 0; kt < 17; ++kt) sv += s[kt][i];
      sv += __shfl_xor(sv, 1);
      sv += __shfl_xor(sv, 2);
      sv += __shfl_xor(sv, 4);
      sv += __shfl_xor(sv, 8);
      den[i] = sv;
    }
    // write unnormalized P (bf16) to wave-private LDS
#pragma unroll
    for (int kt = 0; kt < 17; ++kt)
#pragma unroll
      for (int i = 0; i < 4; ++i)
        P[wid][(((lane >> 4) << 2) + i) * PSTR + kt * 16 + (lane & 15)] = f2bf(s[kt][i]);
    asm volatile("s_waitcnt lgkmcnt(0)" ::: "memory");

    f32x4 oa = (f32x4)0.0f, ob = (f32x4)0.0f;
#pragma unroll
    for (int kc = 0; kc < 9; ++kc) {
      const short8 pf = *(const short8*)(P[wid] + (lane & 15) * PSTR + kc * 32 + ((lane >> 4) << 3));
      const short8 v0 = *(const short8*)(Vt + (lane & 15) * VSTR + kc * 32 + ((lane >> 4) << 3));
      const short8 v1 = *(const short8*)(Vt + (16 + (lane & 15)) * VSTR + kc * 32 + ((lane >> 4) << 3));
      oa = __builtin_amdgcn_mfma_f32_16x16x32_bf16(pf, v0, oa, 0, 0, 0);
      ob = __builtin_amdgcn_mfma_f32_16x16x32_bf16(pf, v1, ob, 0, 0, 0);
    }
#pragma unroll
    for (int i = 0; i < 4; ++i) {
      const int q = qt * 16 + ((lane >> 4) << 2) + i;
      if (q < 257) {
        const float inv = 1.0f / den[i];
        O[base + ((size_t)q << 8) + (lane & 15)] = f2bf(oa[i] * inv);
        O[base + ((size_t)q << 8) + 16 + (lane & 15)] = f2bf(ob[i] * inv);
      }
    }
  }
}

// ---------------- row LayerNorm (256 cols), one row per wave; in-place safe ----------------
template<int WB16>
__global__ __launch_bounds__(256) void ln_k(const float* __restrict__ in,
                                            const float* __restrict__ gamma,
                                            const float* __restrict__ beta,
                                            float* __restrict__ o32,
                                            ushort* __restrict__ o16) {
  const int lane = threadIdx.x & 63, wid = threadIdx.x >> 6;
  const size_t r = (size_t)blockIdx.x * 4 + wid;
  const float4 v = *(const float4*)(in + (r << 8) + (lane << 2));
  float s = v.x + v.y + v.z + v.w;
#pragma unroll
  for (int m = 1; m < 64; m <<= 1) s += __shfl_xor(s, m);
  const float mu = s * (1.0f / 256.0f);
  float4 d; d.x = v.x - mu; d.y = v.y - mu; d.z = v.z - mu; d.w = v.w - mu;
  float ss = d.x * d.x + d.y * d.y + d.z * d.z + d.w * d.w;
#pragma unroll
  for (int m = 1; m < 64; m <<= 1) ss += __shfl_xor(ss, m);
  const float rs = rsqrtf(ss * (1.0f / 256.0f) + 1e-5f);
  const float4 gv = *(const float4*)(gamma + (lane << 2));
  const float4 bv = *(const float4*)(beta + (lane << 2));
  float4 o;
  o.x = d.x * rs * gv.x + bv.x; o.y = d.y * rs * gv.y + bv.y;
  o.z = d.z * rs * gv.z + bv.z; o.w = d.w * rs * gv.w + bv.w;
  *(float4*)(o32 + (r << 8) + (lane << 2)) = o;
  if constexpr (WB16) {
    ushort4v u;
    u[0] = f2bf(o.x); u[1] = f2bf(o.y); u[2] = f2bf(o.z); u[3] = f2bf(o.w);
    *(ushort4v*)(o16 + (r << 8) + (lane << 2)) = u;
  }
}

extern "C" void kernel_launch(void* const* d_in, const int* in_sizes, int n_in,
                              void* d_out, int out_size, void* d_ws, size_t ws_size,
                              hipStream_t stream) {
  (void)in_sizes; (void)n_in; (void)out_size; (void)ws_size;
  const float* x     = (const float*)d_in[0];
  const int*   batch = (const int*)d_in[1];
  const float* cls   = (const float*)d_in[2];
  const float* Wq    = (const float*)d_in[3];
  const float* bq    = (const float*)d_in[4];
  const float* Wk    = (const float*)d_in[5];
  const float* bk    = (const float*)d_in[6];
  const float* Wv    = (const float*)d_in[7];
  const float* bv    = (const float*)d_in[8];
  const float* Wo    = (const float*)d_in[9];
  const float* bo    = (const float*)d_in[10];
  const float* g0    = (const float*)d_in[11];
  const float* beta0 = (const float*)d_in[12];
  const float* W1    = (const float*)d_in[13];
  const float* b1    = (const float*)d_in[14];
  const float* W2    = (const float*)d_in[15];
  const float* b2    = (const float*)d_in[16];
  const float* g1    = (const float*)d_in[17];
  const float* beta1 = (const float*)d_in[18];

  // Workspace plan (peak 102.1 MB):
  //   ws[0..4KB)        start[257]
  //   ws[4KB..1.05MB)   Wt (6 transposed bf16 weights)
  //   base+0    S1 (33.7MB): Q  -> attn-out (in-place) -> hln16 (bf16 LN0 out)
  //   base+33.7 S2+S3 (67.4MB): K,V -> hpre (fp32) -> tmid (bf16 65792x512)
  // d_out (67.4MB fp32) doubles as scratch:
  //   xd (bf16 dense input) -> hln (fp32 LN0 out) -> f+h (in-place) -> final LN1 (in-place)
  char* ws = (char*)d_ws;
  int*    start = (int*)ws;
  ushort* Wt    = (ushort*)(ws + 4096);
  char*   sbase = ws + 1052672;
  ushort* Qb    = (ushort*)(sbase);
  ushort* Kb2   = (ushort*)(sbase + 33685504);
  ushort* Vb2   = (ushort*)(sbase + 67371008);
  float*  hpre  = (float*)(sbase + 33685504);
  ushort* hln16 = Qb;
  ushort* tmid  = (ushort*)(sbase + 33685504);
  ushort* xd    = (ushort*)d_out;
  float*  hln   = (float*)d_out;
  float*  out   = (float*)d_out;

  seg_start_k<<<256, 256, 0, stream>>>(batch, start);
  prep_w_k<<<dim3(512, 6), 256, 0, stream>>>(Wq, Wk, Wv, Wo, W1, W2, Wt);
  pack_xd_k<<<8224, 256, 0, stream>>>(x, cls, start, xd);
  gemm_k<0><<<dim3(514, 2, 3), 256, 0, stream>>>(xd, Wt, 256, 256, bq, bk, bv,
      Qb, Kb2, Vb2, nullptr, nullptr, nullptr, nullptr, nullptr);
  attn_k<<<2048, 256, 0, stream>>>(Qb, Kb2, Vb2, start, Qb);   // O aliases Q (safe)
  gemm_k<1><<<dim3(514, 2), 256, 0, stream>>>(Qb, Wt + 196608, 256, 256, bo, nullptr, nullptr,
      nullptr, nullptr, nullptr, hpre, x, cls, start, nullptr);
  ln_k<1><<<16448, 256, 0, stream>>>(hpre, g0, beta0, hln, hln16);
  gemm_k<2><<<dim3(514, 4), 256, 0, stream>>>(hln16, Wt + 262144, 512, 256, b1, nullptr, nullptr,
      tmid, nullptr, nullptr, nullptr, nullptr, nullptr, nullptr, nullptr);
  gemm_k<3><<<dim3(514, 2), 256, 0, stream>>>(tmid, Wt + 393216, 256, 512, b2, nullptr, nullptr,
      nullptr, nullptr, nullptr, hln, nullptr, nullptr, nullptr, hln);  // in-place f+h
  ln_k<0><<<16448, 256, 0, stream>>>(hln, g1, beta1, out, nullptr);
}